// Round 3
// baseline (331.495 us; speedup 1.0000x reference)
//
#include <hip/hip_runtime.h>
#include <hip/hip_bf16.h>
#include <hip/hip_fp16.h>

// Problem constants (match reference)
constexpr int IMG_ = 256;
constexpr int M_   = 1920;   // N_SHOTS * N_SAMPLES
constexpr int B_   = 64;
constexpr int MI_  = M_ * IMG_;          // 491520 elements per phase table
constexpr int IMG2 = IMG_ * IMG_;        // 65536

typedef _Float16 half8 __attribute__((ext_vector_type(8)));
typedef float floatx16 __attribute__((ext_vector_type(16)));

// Async 16B global->LDS copy. LDS dest = wave-uniform base + lane*16.
__device__ inline void gl_lds16(const void* g, void* l) {
  __builtin_amdgcn_global_load_lds(
      (const __attribute__((address_space(1))) unsigned int*)g,
      (__attribute__((address_space(3))) unsigned int*)l, 16, 0, 0);
}

// ---------------------------------------------------------------------------
// Phase tables, natural layout [m][i] (f16)
// ---------------------------------------------------------------------------
__global__ __launch_bounds__(256) void phase1_k(
    const float* __restrict__ samples,
    _Float16* __restrict__ axh_r, _Float16* __restrict__ axh_i,
    _Float16* __restrict__ ayh_r, _Float16* __restrict__ ayh_i) {
  int idx = blockIdx.x * 256 + threadIdx.x;
  if (idx >= MI_) return;
  int m = idx >> 8;
  int i = idx & 255;
  float g  = (float)i - 128.0f;
  float kx = samples[2 * m + 0];
  float ky = samples[2 * m + 1];
  float sx, cx, sy, cy;
  sincospif(-2.0f * kx * g, &sx, &cx);
  sincospif(-2.0f * ky * g, &sy, &cy);
  axh_r[idx] = (_Float16)cx; axh_i[idx] = (_Float16)sx;
  ayh_r[idx] = (_Float16)cy; ayh_i[idx] = (_Float16)sy;
}

// Transposed, pre-conjugated tables [pixel][m] (f16) for the adjoint pass.
__global__ __launch_bounds__(256) void phase2_k(
    const float* __restrict__ samples,
    _Float16* __restrict__ axtc_r, _Float16* __restrict__ axtc_i,
    _Float16* __restrict__ aytc_r, _Float16* __restrict__ aytc_i) {
  int m = blockIdx.x * 256 + threadIdx.x;
  if (m >= M_) return;
  int i = blockIdx.y;
  float g  = (float)i - 128.0f;
  float kx = samples[2 * m + 0];
  float ky = samples[2 * m + 1];
  float sx, cx, sy, cy;
  sincospif(-2.0f * kx * g, &sx, &cx);
  sincospif(-2.0f * ky * g, &sy, &cy);
  int o = i * M_ + m;
  axtc_r[o] = (_Float16)cx; axtc_i[o] = (_Float16)(-sx);  // conj(Ax)^T
  aytc_r[o] = (_Float16)cy; aytc_i[o] = (_Float16)(-sy);  // conj(Ay)^T
}

// ---------------------------------------------------------------------------
// X transpose + f16 convert: xth[b][j][i] = x[b][i][j]  (B-operand for fwd)
// ---------------------------------------------------------------------------
__global__ __launch_bounds__(256) void xt_k(
    const float* __restrict__ xr, const float* __restrict__ xi,
    _Float16* __restrict__ xth_r, _Float16* __restrict__ xth_i) {
  __shared__ float tr[32][33], ti[32][33];
  const int t = threadIdx.x;
  const int b = blockIdx.z;
  const int i0 = blockIdx.x * 32, j0 = blockIdx.y * 32;
  const int r = t >> 5, c = t & 31;
#pragma unroll
  for (int k = 0; k < 4; ++k) {
    int row = r + k * 8;
    tr[row][c] = xr[(size_t)b * IMG2 + (i0 + row) * IMG_ + j0 + c];
    ti[row][c] = xi[(size_t)b * IMG2 + (i0 + row) * IMG_ + j0 + c];
  }
  __syncthreads();
#pragma unroll
  for (int k = 0; k < 4; ++k) {
    int row = r + k * 8;
    xth_r[(size_t)b * IMG2 + (j0 + row) * IMG_ + i0 + c] = (_Float16)tr[c][row];
    xth_i[(size_t)b * IMG2 + (j0 + row) * IMG_ + i0 + c] = (_Float16)ti[c][row];
  }
}

// ---------------------------------------------------------------------------
// Forward NDFT via 32x32x16 f16 MFMA (2x2 blocking) + fused Ay j-reduction.
//   kspace[b,m] = sum_j Ay[m,j] * (sum_i Ax[m,i] * X_b[i,j]);  kw = K*density
// Block: 128 m-rows x full j (2 tiles of 128). 4 waves; wave w = (mw,jw) of
// 64x64 complex. LDS tiles: swizzled rows of 32 halfs, staged by
// global_load_lds (16B, lane-contiguous) with XOR chunk swizzle so frag reads
// are conflict-floor ds_read_b128.
// ---------------------------------------------------------------------------
__global__ __launch_bounds__(256, 2) void fwd_k(
    const _Float16* __restrict__ axh_r, const _Float16* __restrict__ axh_i,
    const _Float16* __restrict__ ayh_r, const _Float16* __restrict__ ayh_i,
    const _Float16* __restrict__ xth_r, const _Float16* __restrict__ xth_i,
    const float* __restrict__ density,
    _Float16* __restrict__ kwh_r, _Float16* __restrict__ kwh_i) {
  __shared__ _Float16 sA[2 * 128 * 32];   // [0]=re, [4096]=im
  __shared__ _Float16 sB[2 * 128 * 32];
  __shared__ float kred[2][128][2];       // [jw-half][m-local][re/im]

  const int t  = threadIdx.x;
  const int w  = t >> 6, l = t & 63;
  const int lo = l & 31, hi = l >> 5;
  const int mw = (w & 1) * 64;
  const int jwb = w >> 1;
  const int jw = jwb * 64;
  const int m0 = blockIdx.x * 128;
  const int b  = blockIdx.y;

  ((float*)kred)[t] = 0.f;
  ((float*)kred)[t + 256] = 0.f;

  const _Float16* __restrict__ xb_r = xth_r + (size_t)b * IMG2;
  const _Float16* __restrict__ xb_i = xth_i + (size_t)b * IMG2;

  const floatx16 z16 = {0.f,0.f,0.f,0.f,0.f,0.f,0.f,0.f,0.f,0.f,0.f,0.f,0.f,0.f,0.f,0.f};

  for (int jc = 0; jc < 2; ++jc) {
    const int j0 = jc * 128;
    floatx16 accr[2][2] = {{z16, z16}, {z16, z16}};
    floatx16 acci[2][2] = {{z16, z16}, {z16, z16}};

    for (int kt = 0; kt < 8; ++kt) {
      const int i0 = kt * 32;
      __syncthreads();
#pragma unroll
      for (int p = 0; p < 2; ++p) {
        int s  = w * 2 + p;              // slice 0..7 (wave-uniform)
        int q  = s * 64 + l;             // slot 0..511
        int r  = q >> 2;                 // tile row
        int cl = (q & 3) ^ (r & 3);      // logical 16B chunk (XOR swizzle)
        int ga = (m0 + r) * IMG_ + i0 + cl * 8;
        int gb = (j0 + r) * IMG_ + i0 + cl * 8;
        gl_lds16(axh_r + ga, &sA[s * 512]);
        gl_lds16(axh_i + ga, &sA[4096 + s * 512]);
        gl_lds16(xb_r  + gb, &sB[s * 512]);
        gl_lds16(xb_i  + gb, &sB[4096 + s * 512]);
      }
      __syncthreads();

#pragma unroll
      for (int ks = 0; ks < 2; ++ks) {
        half8 ar[2], ai[2], nai[2], br[2], bi[2];
#pragma unroll
        for (int tm = 0; tm < 2; ++tm) {
          int rt  = mw + tm * 32 + lo;
          int off = rt * 32 + ((ks * 2 + hi) ^ (rt & 3)) * 8;
          ar[tm]  = *(const half8*)&sA[off];
          ai[tm]  = *(const half8*)&sA[4096 + off];
          nai[tm] = -ai[tm];
        }
#pragma unroll
        for (int tj = 0; tj < 2; ++tj) {
          int rt  = jw + tj * 32 + lo;
          int off = rt * 32 + ((ks * 2 + hi) ^ (rt & 3)) * 8;
          br[tj]  = *(const half8*)&sB[off];
          bi[tj]  = *(const half8*)&sB[4096 + off];
        }
#pragma unroll
        for (int tm = 0; tm < 2; ++tm)
#pragma unroll
          for (int tj = 0; tj < 2; ++tj) {
            accr[tm][tj] = __builtin_amdgcn_mfma_f32_32x32x16_f16(ar[tm],  br[tj], accr[tm][tj], 0, 0, 0);
            accr[tm][tj] = __builtin_amdgcn_mfma_f32_32x32x16_f16(nai[tm], bi[tj], accr[tm][tj], 0, 0, 0);
            acci[tm][tj] = __builtin_amdgcn_mfma_f32_32x32x16_f16(ar[tm],  bi[tj], acci[tm][tj], 0, 0, 0);
            acci[tm][tj] = __builtin_amdgcn_mfma_f32_32x32x16_f16(ai[tm],  br[tj], acci[tm][tj], 0, 0, 0);
          }
      }
    }

    // Epilogue: kred[m] += sum_j Ay[m,j]*T[m,j]
    // C layout: col = lo (j), row = (reg&3) + 8*(reg>>2) + 4*hi
#pragma unroll
    for (int tm = 0; tm < 2; ++tm) {
#pragma unroll
      for (int reg = 0; reg < 16; ++reg) {
        int row = (reg & 3) + 8 * (reg >> 2) + 4 * hi;
        int m = m0 + mw + tm * 32 + row;
        float wr = 0.f, wi = 0.f;
#pragma unroll
        for (int tj = 0; tj < 2; ++tj) {
          int j = j0 + jw + tj * 32 + lo;
          float yr = (float)ayh_r[m * IMG_ + j];
          float yi = (float)ayh_i[m * IMG_ + j];
          float tr = accr[tm][tj][reg], ti = acci[tm][tj][reg];
          wr = fmaf(yr, tr, fmaf(-yi, ti, wr));
          wi = fmaf(yr, ti, fmaf(yi, tr, wi));
        }
#pragma unroll
        for (int off = 1; off < 32; off <<= 1) {
          wr += __shfl_xor(wr, off);
          wi += __shfl_xor(wi, off);
        }
        if (lo == 0) {
          int ml = mw + tm * 32 + row;
          kred[jwb][ml][0] += wr;
          kred[jwb][ml][1] += wi;
        }
      }
    }
  }

  __syncthreads();
  if (t < 128) {
    int m = m0 + t;
    float rr = kred[0][t][0] + kred[1][t][0];
    float ii = kred[0][t][1] + kred[1][t][1];
    float d  = density[m];
    kwh_r[b * M_ + m] = (_Float16)(rr * d);
    kwh_i[b * M_ + m] = (_Float16)(ii * d);
  }
}

// ---------------------------------------------------------------------------
// Adjoint NDFT via 32x32x16 f16 MFMA (2x2 blocking):
//   out[b,i,j] = (1/IMG^2) sum_m [conj(Ax)[m,i]*kw[b,m]] * conj(Ay)[m,j]
// A' = axtc * kw computed during staging (packed f16 vec math, swizzled
// ds_write_b128); B = aytc streamed by global_load_lds. K = M = 1920.
// ---------------------------------------------------------------------------
__global__ __launch_bounds__(256, 2) void adj_k(
    const _Float16* __restrict__ axtc_r, const _Float16* __restrict__ axtc_i,
    const _Float16* __restrict__ aytc_r, const _Float16* __restrict__ aytc_i,
    const _Float16* __restrict__ kwh_r, const _Float16* __restrict__ kwh_i,
    float* __restrict__ out) {
  __shared__ _Float16 sA[2 * 128 * 32];   // A' re/im
  __shared__ _Float16 sB[2 * 128 * 32];   // conj(Ay)^T re/im

  const int t  = threadIdx.x;
  const int w  = t >> 6, l = t & 63;
  const int lo = l & 31, hi = l >> 5;
  const int iw = (w & 1) * 64;
  const int jw = (w >> 1) * 64;
  const int i0 = blockIdx.x * 128;
  const int j0 = blockIdx.y * 128;
  const int b  = blockIdx.z;

  const floatx16 z16 = {0.f,0.f,0.f,0.f,0.f,0.f,0.f,0.f,0.f,0.f,0.f,0.f,0.f,0.f,0.f,0.f};
  floatx16 accr[2][2] = {{z16, z16}, {z16, z16}};
  floatx16 acci[2][2] = {{z16, z16}, {z16, z16}};

  for (int mt = 0; mt < M_ / 32; ++mt) {
    const int m0 = mt * 32;
    __syncthreads();
    // B: pure table, async direct-to-LDS (issue first to overlap with A' math)
#pragma unroll
    for (int p = 0; p < 2; ++p) {
      int s  = w * 2 + p;
      int q  = s * 64 + l;
      int r  = q >> 2;
      int cl = (q & 3) ^ (r & 3);
      int gb = (j0 + r) * M_ + m0 + cl * 8;
      gl_lds16(aytc_r + gb, &sB[s * 512]);
      gl_lds16(aytc_i + gb, &sB[4096 + s * 512]);
    }
    // A' = conj(Ax)^T * kw : computed, stored with the same swizzle
#pragma unroll
    for (int p = 0; p < 2; ++p) {
      int q  = p * 256 + t;
      int r  = q >> 2;
      int cl = (q & 3) ^ (r & 3);
      int ga = (i0 + r) * M_ + m0 + cl * 8;
      half8 xr8 = *(const half8*)&axtc_r[ga];
      half8 xi8 = *(const half8*)&axtc_i[ga];
      half8 kr8 = *(const half8*)&kwh_r[b * M_ + m0 + cl * 8];
      half8 ki8 = *(const half8*)&kwh_i[b * M_ + m0 + cl * 8];
      half8 wr8 = xr8 * kr8 - xi8 * ki8;
      half8 wi8 = xr8 * ki8 + xi8 * kr8;
      *(half8*)&sA[q * 8]        = wr8;
      *(half8*)&sA[4096 + q * 8] = wi8;
    }
    __syncthreads();

#pragma unroll
    for (int ks = 0; ks < 2; ++ks) {
      half8 ar[2], ai[2], nai[2], br[2], bi[2];
#pragma unroll
      for (int tm = 0; tm < 2; ++tm) {
        int rt  = iw + tm * 32 + lo;
        int off = rt * 32 + ((ks * 2 + hi) ^ (rt & 3)) * 8;
        ar[tm]  = *(const half8*)&sA[off];
        ai[tm]  = *(const half8*)&sA[4096 + off];
        nai[tm] = -ai[tm];
      }
#pragma unroll
      for (int tj = 0; tj < 2; ++tj) {
        int rt  = jw + tj * 32 + lo;
        int off = rt * 32 + ((ks * 2 + hi) ^ (rt & 3)) * 8;
        br[tj]  = *(const half8*)&sB[off];
        bi[tj]  = *(const half8*)&sB[4096 + off];
      }
#pragma unroll
      for (int tm = 0; tm < 2; ++tm)
#pragma unroll
        for (int tj = 0; tj < 2; ++tj) {
          accr[tm][tj] = __builtin_amdgcn_mfma_f32_32x32x16_f16(ar[tm],  br[tj], accr[tm][tj], 0, 0, 0);
          accr[tm][tj] = __builtin_amdgcn_mfma_f32_32x32x16_f16(nai[tm], bi[tj], accr[tm][tj], 0, 0, 0);
          acci[tm][tj] = __builtin_amdgcn_mfma_f32_32x32x16_f16(ar[tm],  bi[tj], acci[tm][tj], 0, 0, 0);
          acci[tm][tj] = __builtin_amdgcn_mfma_f32_32x32x16_f16(ai[tm],  br[tj], acci[tm][tj], 0, 0, 0);
        }
    }
  }

  const float s = 1.0f / (float)IMG2;
#pragma unroll
  for (int tm = 0; tm < 2; ++tm)
#pragma unroll
    for (int tj = 0; tj < 2; ++tj)
#pragma unroll
      for (int reg = 0; reg < 16; ++reg) {
        int row = (reg & 3) + 8 * (reg >> 2) + 4 * hi;
        int ig = i0 + iw + tm * 32 + row;
        int jg = j0 + jw + tj * 32 + lo;
        float2 v = make_float2(accr[tm][tj][reg] * s, acci[tm][tj][reg] * s);
        *(float2*)&out[((size_t)(b * IMG_ + ig) * IMG_ + jg) * 2] = v;
      }
}

// ---------------------------------------------------------------------------
// Launch
// ---------------------------------------------------------------------------
extern "C" void kernel_launch(void* const* d_in, const int* in_sizes, int n_in,
                              void* d_out, int out_size, void* d_ws, size_t ws_size,
                              hipStream_t stream) {
  (void)in_sizes; (void)n_in; (void)out_size; (void)ws_size;

  const float* xr      = (const float*)d_in[0];
  const float* xi      = (const float*)d_in[1];
  const float* samples = (const float*)d_in[2];
  const float* density = (const float*)d_in[3];
  float* out = (float*)d_out;

  _Float16* f = (_Float16*)d_ws;
  _Float16* axh_r  = f + 0 * MI_;
  _Float16* axh_i  = f + 1 * MI_;
  _Float16* ayh_r  = f + 2 * MI_;
  _Float16* ayh_i  = f + 3 * MI_;
  _Float16* axtc_r = f + 4 * MI_;
  _Float16* axtc_i = f + 5 * MI_;
  _Float16* aytc_r = f + 6 * MI_;
  _Float16* aytc_i = f + 7 * MI_;
  _Float16* kwh_r  = f + 8 * MI_;
  _Float16* kwh_i  = kwh_r + B_ * M_;

  // X^T (f16) parked in d_out; fully consumed by fwd_k before adj_k overwrites.
  _Float16* xth_r = (_Float16*)d_out;
  _Float16* xth_i = xth_r + (size_t)B_ * IMG2;

  phase1_k<<<(MI_ + 255) / 256, 256, 0, stream>>>(samples, axh_r, axh_i, ayh_r, ayh_i);
  phase2_k<<<dim3(8, IMG_), 256, 0, stream>>>(samples, axtc_r, axtc_i, aytc_r, aytc_i);
  xt_k<<<dim3(8, 8, B_), 256, 0, stream>>>(xr, xi, xth_r, xth_i);
  fwd_k<<<dim3(M_ / 128, B_), 256, 0, stream>>>(axh_r, axh_i, ayh_r, ayh_i,
                                                xth_r, xth_i, density, kwh_r, kwh_i);
  adj_k<<<dim3(2, 2, B_), 256, 0, stream>>>(axtc_r, axtc_i, aytc_r, aytc_i,
                                            kwh_r, kwh_i, out);
}

// Round 4
// 301.980 us; speedup vs baseline: 1.0977x; 1.0977x over previous
//
#include <hip/hip_runtime.h>
#include <hip/hip_fp16.h>

// Problem constants (match reference)
constexpr int IMG_ = 256;
constexpr int M_   = 1920;   // N_SHOTS * N_SAMPLES
constexpr int B_   = 64;
constexpr int MI_  = M_ * IMG_;          // 491520 elements per phase table
constexpr int IMG2 = IMG_ * IMG_;        // 65536

typedef _Float16 half8 __attribute__((ext_vector_type(8)));
typedef float floatx16 __attribute__((ext_vector_type(16)));

// Async 16B global->LDS copy. LDS dest = wave-uniform base + lane*16.
__device__ inline void gl_lds16(const void* g, void* l) {
  __builtin_amdgcn_global_load_lds(
      (const __attribute__((address_space(1))) unsigned int*)g,
      (__attribute__((address_space(3))) unsigned int*)l, 16, 0, 0);
}

// ---------------------------------------------------------------------------
// Phase tables, natural layout [m][i] (f16)
// ---------------------------------------------------------------------------
__global__ __launch_bounds__(256) void phase1_k(
    const float* __restrict__ samples,
    _Float16* __restrict__ axh_r, _Float16* __restrict__ axh_i,
    _Float16* __restrict__ ayh_r, _Float16* __restrict__ ayh_i) {
  int idx = blockIdx.x * 256 + threadIdx.x;
  if (idx >= MI_) return;
  int m = idx >> 8;
  int i = idx & 255;
  float g  = (float)i - 128.0f;
  float kx = samples[2 * m + 0];
  float ky = samples[2 * m + 1];
  float sx, cx, sy, cy;
  sincospif(-2.0f * kx * g, &sx, &cx);
  sincospif(-2.0f * ky * g, &sy, &cy);
  axh_r[idx] = (_Float16)cx; axh_i[idx] = (_Float16)sx;
  ayh_r[idx] = (_Float16)cy; ayh_i[idx] = (_Float16)sy;
}

// Transposed, pre-conjugated tables [pixel][m] (f16) for the adjoint pass.
__global__ __launch_bounds__(256) void phase2_k(
    const float* __restrict__ samples,
    _Float16* __restrict__ axtc_r, _Float16* __restrict__ axtc_i,
    _Float16* __restrict__ aytc_r, _Float16* __restrict__ aytc_i) {
  int m = blockIdx.x * 256 + threadIdx.x;
  if (m >= M_) return;
  int i = blockIdx.y;
  float g  = (float)i - 128.0f;
  float kx = samples[2 * m + 0];
  float ky = samples[2 * m + 1];
  float sx, cx, sy, cy;
  sincospif(-2.0f * kx * g, &sx, &cx);
  sincospif(-2.0f * ky * g, &sy, &cy);
  int o = i * M_ + m;
  axtc_r[o] = (_Float16)cx; axtc_i[o] = (_Float16)(-sx);  // conj(Ax)^T
  aytc_r[o] = (_Float16)cy; aytc_i[o] = (_Float16)(-sy);  // conj(Ay)^T
}

// ---------------------------------------------------------------------------
// X f32 -> f16, natural layout (no transpose needed with j-first contraction)
// ---------------------------------------------------------------------------
__global__ __launch_bounds__(256) void xcvt_k(
    const float* __restrict__ xr, const float* __restrict__ xi,
    _Float16* __restrict__ xh_r, _Float16* __restrict__ xh_i) {
  int idx = (blockIdx.x * 256 + threadIdx.x) * 8;
  float4 a = *(const float4*)&xr[idx];
  float4 c = *(const float4*)&xr[idx + 4];
  half8 h;
  h[0] = (_Float16)a.x; h[1] = (_Float16)a.y; h[2] = (_Float16)a.z; h[3] = (_Float16)a.w;
  h[4] = (_Float16)c.x; h[5] = (_Float16)c.y; h[6] = (_Float16)c.z; h[7] = (_Float16)c.w;
  *(half8*)&xh_r[idx] = h;
  a = *(const float4*)&xi[idx];
  c = *(const float4*)&xi[idx + 4];
  h[0] = (_Float16)a.x; h[1] = (_Float16)a.y; h[2] = (_Float16)a.z; h[3] = (_Float16)a.w;
  h[4] = (_Float16)c.x; h[5] = (_Float16)c.y; h[6] = (_Float16)c.z; h[7] = (_Float16)c.w;
  *(half8*)&xh_i[idx] = h;
}

// ---------------------------------------------------------------------------
// Forward NDFT, j-first contraction:
//   V[m,i] = sum_j Ay[m,j] * X_b[i,j]   (MFMA GEMM, K = j = 256)
//   K[m]   = sum_i Ax[m,i] * V[m,i]     (epilogue weighted reduce)
// Block 256 thr = 4 waves (2x2 of 64m x 64i); 128 m-rows/block, i in 2 halves.
// Double-buffered LDS, ONE barrier per K-step: prefetch k+1 issued after the
// barrier so the compiler's vmcnt(0)-before-barrier lands after compute.
// ---------------------------------------------------------------------------
__global__ __launch_bounds__(256, 2) void fwd_k(
    const _Float16* __restrict__ axh_r, const _Float16* __restrict__ axh_i,
    const _Float16* __restrict__ ayh_r, const _Float16* __restrict__ ayh_i,
    const _Float16* __restrict__ xh_r, const _Float16* __restrict__ xh_i,
    const float* __restrict__ density,
    _Float16* __restrict__ kwh_r, _Float16* __restrict__ kwh_i) {
  __shared__ _Float16 sA[2][2 * 128 * 32];   // Ay tile: [buf][re|im][128m x 32j]
  __shared__ _Float16 sB[2][2 * 128 * 32];   // X tile:  [buf][re|im][128i x 32j]
  __shared__ float kred[2][128][2];          // [i-wave-half][m-local][re/im]

  const int t  = threadIdx.x;
  const int w  = t >> 6, l = t & 63;
  const int lo = l & 31, hi = l >> 5;
  const int mw  = (w & 1) * 64;
  const int iwb = w >> 1;
  const int iw  = iwb * 64;
  const int m0 = blockIdx.x * 128;
  const int b  = blockIdx.y;

  ((float*)kred)[t]       = 0.f;
  ((float*)kred)[t + 256] = 0.f;

  const _Float16* __restrict__ xbr = xh_r + (size_t)b * IMG2;
  const _Float16* __restrict__ xbi = xh_i + (size_t)b * IMG2;

  const floatx16 z16 = {0.f,0.f,0.f,0.f,0.f,0.f,0.f,0.f,0.f,0.f,0.f,0.f,0.f,0.f,0.f,0.f};
  floatx16 accr[2][2], acci[2][2];

  auto stage = [&](int kt, int buf, int ic) {
    const int j0 = kt * 32;
#pragma unroll
    for (int p = 0; p < 2; ++p) {
      int s  = w * 2 + p;              // slice 0..7 (wave-uniform)
      int q  = s * 64 + l;             // slot 0..511
      int r  = q >> 2;                 // tile row
      int cl = (q & 3) ^ (r & 3);      // XOR chunk swizzle
      int ga = (m0 + r) * IMG_ + j0 + cl * 8;
      int gb = (ic * 128 + r) * IMG_ + j0 + cl * 8;
      gl_lds16(ayh_r + ga, &sA[buf][s * 512]);
      gl_lds16(ayh_i + ga, &sA[buf][4096 + s * 512]);
      gl_lds16(xbr + gb,  &sB[buf][s * 512]);
      gl_lds16(xbi + gb,  &sB[buf][4096 + s * 512]);
    }
  };

  auto compute = [&](int buf) {
#pragma unroll
    for (int ks = 0; ks < 2; ++ks) {
      half8 ar[2], ai[2], nai[2], br[2], bi[2];
#pragma unroll
      for (int tm = 0; tm < 2; ++tm) {
        int rt  = mw + tm * 32 + lo;
        int off = rt * 32 + ((ks * 2 + hi) ^ (rt & 3)) * 8;
        ar[tm]  = *(const half8*)&sA[buf][off];
        ai[tm]  = *(const half8*)&sA[buf][4096 + off];
        nai[tm] = -ai[tm];
      }
#pragma unroll
      for (int ti = 0; ti < 2; ++ti) {
        int rt  = iw + ti * 32 + lo;
        int off = rt * 32 + ((ks * 2 + hi) ^ (rt & 3)) * 8;
        br[ti]  = *(const half8*)&sB[buf][off];
        bi[ti]  = *(const half8*)&sB[buf][4096 + off];
      }
#pragma unroll
      for (int tm = 0; tm < 2; ++tm)
#pragma unroll
        for (int ti = 0; ti < 2; ++ti) {
          accr[tm][ti] = __builtin_amdgcn_mfma_f32_32x32x16_f16(ar[tm],  br[ti], accr[tm][ti], 0, 0, 0);
          accr[tm][ti] = __builtin_amdgcn_mfma_f32_32x32x16_f16(nai[tm], bi[ti], accr[tm][ti], 0, 0, 0);
          acci[tm][ti] = __builtin_amdgcn_mfma_f32_32x32x16_f16(ar[tm],  bi[ti], acci[tm][ti], 0, 0, 0);
          acci[tm][ti] = __builtin_amdgcn_mfma_f32_32x32x16_f16(ai[tm],  br[ti], acci[tm][ti], 0, 0, 0);
        }
    }
  };

  for (int ic = 0; ic < 2; ++ic) {
#pragma unroll
    for (int tm = 0; tm < 2; ++tm)
#pragma unroll
      for (int ti = 0; ti < 2; ++ti) { accr[tm][ti] = z16; acci[tm][ti] = z16; }

    stage(0, 0, ic);
    for (int kt = 0; kt < 8; kt += 2) {
      __syncthreads();                 // drains buf0's loads; prefetch after
      stage(kt + 1, 1, ic);
      compute(0);
      __syncthreads();                 // drains buf1's loads
      if (kt + 2 < 8) stage(kt + 2, 0, ic);
      compute(1);
    }

    // Epilogue: kred[m] += sum_i Ax[m,i] * V[m,i]
    // C layout: col = lo (i), row = (reg&3) + 8*(reg>>2) + 4*hi
#pragma unroll
    for (int tm = 0; tm < 2; ++tm) {
#pragma unroll
      for (int reg = 0; reg < 16; ++reg) {
        int row = (reg & 3) + 8 * (reg >> 2) + 4 * hi;
        int m = m0 + mw + tm * 32 + row;
        float wr = 0.f, wi = 0.f;
#pragma unroll
        for (int ti = 0; ti < 2; ++ti) {
          int i = ic * 128 + iw + ti * 32 + lo;
          float xr_ = (float)axh_r[m * IMG_ + i];
          float xi_ = (float)axh_i[m * IMG_ + i];
          float tr = accr[tm][ti][reg], tv = acci[tm][ti][reg];
          wr = fmaf(xr_, tr, fmaf(-xi_, tv, wr));
          wi = fmaf(xr_, tv, fmaf(xi_, tr, wi));
        }
#pragma unroll
        for (int off = 1; off < 32; off <<= 1) {
          wr += __shfl_xor(wr, off);
          wi += __shfl_xor(wi, off);
        }
        if (lo == 0) {
          int ml = mw + tm * 32 + row;
          kred[iwb][ml][0] += wr;
          kred[iwb][ml][1] += wi;
        }
      }
    }
  }

  __syncthreads();
  if (t < 128) {
    int m = m0 + t;
    float rr = kred[0][t][0] + kred[1][t][0];
    float ii = kred[0][t][1] + kred[1][t][1];
    float d  = density[m];
    kwh_r[b * M_ + m] = (_Float16)(rr * d);
    kwh_i[b * M_ + m] = (_Float16)(ii * d);
  }
}

// ---------------------------------------------------------------------------
// Adjoint NDFT: out[b,i,j] = (1/IMG^2) sum_m [conj(Ax)[m,i]*kw[b,m]]*conj(Ay)[m,j]
// 512 thr = 8 waves (each 64i x 32j) on a 128i x 128j tile; K = M = 1920.
// Same single-barrier double-buffered schedule. A' computed during staging.
// ---------------------------------------------------------------------------
__global__ __launch_bounds__(512, 2) void adj_k(
    const _Float16* __restrict__ axtc_r, const _Float16* __restrict__ axtc_i,
    const _Float16* __restrict__ aytc_r, const _Float16* __restrict__ aytc_i,
    const _Float16* __restrict__ kwh_r, const _Float16* __restrict__ kwh_i,
    float* __restrict__ out) {
  __shared__ _Float16 sA[2][2 * 128 * 32];   // A' = conj(Ax)^T * kw
  __shared__ _Float16 sB[2][2 * 128 * 32];   // conj(Ay)^T

  const int t  = threadIdx.x;
  const int w  = t >> 6, l = t & 63;
  const int lo = l & 31, hi = l >> 5;
  const int iw = (w & 1) * 64;
  const int jw = (w >> 1) * 32;
  const int i0 = blockIdx.x * 128;
  const int j0 = blockIdx.y * 128;
  const int b  = blockIdx.z;

  const floatx16 z16 = {0.f,0.f,0.f,0.f,0.f,0.f,0.f,0.f,0.f,0.f,0.f,0.f,0.f,0.f,0.f,0.f};
  floatx16 accr[2] = {z16, z16};
  floatx16 acci[2] = {z16, z16};

  auto stage = [&](int mt, int buf) {
    const int m0 = mt * 32;
    // B: pure table via async direct-to-LDS (16 slices over 8 waves)
#pragma unroll
    for (int p = 0; p < 2; ++p) {
      int s   = w * 2 + p;             // 0..15
      int arr = s >> 3, sl = s & 7;
      int q   = sl * 64 + l;
      int r   = q >> 2;
      int cl  = (q & 3) ^ (r & 3);
      int gb  = (j0 + r) * M_ + m0 + cl * 8;
      const _Float16* src = arr ? aytc_i : aytc_r;
      gl_lds16(src + gb, &sB[buf][arr * 4096 + sl * 512]);
    }
    // A' = conj(Ax)^T * kw, packed f16, swizzled ds_write_b128 (1 slot/thread)
    {
      int q  = t;
      int r  = q >> 2;
      int cl = (q & 3) ^ (r & 3);
      int ga = (i0 + r) * M_ + m0 + cl * 8;
      half8 xr8 = *(const half8*)&axtc_r[ga];
      half8 xi8 = *(const half8*)&axtc_i[ga];
      half8 kr8 = *(const half8*)&kwh_r[b * M_ + m0 + cl * 8];
      half8 ki8 = *(const half8*)&kwh_i[b * M_ + m0 + cl * 8];
      half8 wr8 = xr8 * kr8 - xi8 * ki8;
      half8 wi8 = xr8 * ki8 + xi8 * kr8;
      *(half8*)&sA[buf][q * 8]        = wr8;
      *(half8*)&sA[buf][4096 + q * 8] = wi8;
    }
  };

  auto compute = [&](int buf) {
#pragma unroll
    for (int ks = 0; ks < 2; ++ks) {
      half8 ar[2], ai[2], nai[2], br, bi;
#pragma unroll
      for (int tm = 0; tm < 2; ++tm) {
        int rt  = iw + tm * 32 + lo;
        int off = rt * 32 + ((ks * 2 + hi) ^ (rt & 3)) * 8;
        ar[tm]  = *(const half8*)&sA[buf][off];
        ai[tm]  = *(const half8*)&sA[buf][4096 + off];
        nai[tm] = -ai[tm];
      }
      {
        int rt  = jw + lo;
        int off = rt * 32 + ((ks * 2 + hi) ^ (rt & 3)) * 8;
        br = *(const half8*)&sB[buf][off];
        bi = *(const half8*)&sB[buf][4096 + off];
      }
#pragma unroll
      for (int tm = 0; tm < 2; ++tm) {
        accr[tm] = __builtin_amdgcn_mfma_f32_32x32x16_f16(ar[tm],  br, accr[tm], 0, 0, 0);
        accr[tm] = __builtin_amdgcn_mfma_f32_32x32x16_f16(nai[tm], bi, accr[tm], 0, 0, 0);
        acci[tm] = __builtin_amdgcn_mfma_f32_32x32x16_f16(ar[tm],  bi, acci[tm], 0, 0, 0);
        acci[tm] = __builtin_amdgcn_mfma_f32_32x32x16_f16(ai[tm],  br, acci[tm], 0, 0, 0);
      }
    }
  };

  stage(0, 0);
  for (int mt = 0; mt < M_ / 32; mt += 2) {
    __syncthreads();
    stage(mt + 1, 1);
    compute(0);
    __syncthreads();
    if (mt + 2 < M_ / 32) stage(mt + 2, 0);
    compute(1);
  }

  const float s = 1.0f / (float)IMG2;
#pragma unroll
  for (int tm = 0; tm < 2; ++tm)
#pragma unroll
    for (int reg = 0; reg < 16; ++reg) {
      int row = (reg & 3) + 8 * (reg >> 2) + 4 * hi;
      int ig = i0 + iw + tm * 32 + row;
      int jg = j0 + jw + lo;
      float2 v = make_float2(accr[tm][reg] * s, acci[tm][reg] * s);
      *(float2*)&out[((size_t)(b * IMG_ + ig) * IMG_ + jg) * 2] = v;
    }
}

// ---------------------------------------------------------------------------
// Launch
// ---------------------------------------------------------------------------
extern "C" void kernel_launch(void* const* d_in, const int* in_sizes, int n_in,
                              void* d_out, int out_size, void* d_ws, size_t ws_size,
                              hipStream_t stream) {
  (void)in_sizes; (void)n_in; (void)out_size; (void)ws_size;

  const float* xr      = (const float*)d_in[0];
  const float* xi      = (const float*)d_in[1];
  const float* samples = (const float*)d_in[2];
  const float* density = (const float*)d_in[3];
  float* out = (float*)d_out;

  _Float16* f = (_Float16*)d_ws;
  _Float16* axh_r  = f + 0 * MI_;
  _Float16* axh_i  = f + 1 * MI_;
  _Float16* ayh_r  = f + 2 * MI_;
  _Float16* ayh_i  = f + 3 * MI_;
  _Float16* axtc_r = f + 4 * MI_;
  _Float16* axtc_i = f + 5 * MI_;
  _Float16* aytc_r = f + 6 * MI_;
  _Float16* aytc_i = f + 7 * MI_;
  _Float16* kwh_r  = f + 8 * MI_;
  _Float16* kwh_i  = kwh_r + B_ * M_;

  // X (f16, natural layout) parked in d_out; consumed by fwd_k before adj_k
  // overwrites d_out with the final result.
  _Float16* xh_r = (_Float16*)d_out;
  _Float16* xh_i = xh_r + (size_t)B_ * IMG2;

  phase1_k<<<(MI_ + 255) / 256, 256, 0, stream>>>(samples, axh_r, axh_i, ayh_r, ayh_i);
  phase2_k<<<dim3(8, IMG_), 256, 0, stream>>>(samples, axtc_r, axtc_i, aytc_r, aytc_i);
  xcvt_k<<<(B_ * IMG2) / 8 / 256, 256, 0, stream>>>(xr, xi, xh_r, xh_i);
  fwd_k<<<dim3(M_ / 128, B_), 256, 0, stream>>>(axh_r, axh_i, ayh_r, ayh_i,
                                                xh_r, xh_i, density, kwh_r, kwh_i);
  adj_k<<<dim3(2, 2, B_), 512, 0, stream>>>(axtc_r, axtc_i, aytc_r, aytc_i,
                                            kwh_r, kwh_i, out);
}